// Round 1
// baseline (647.538 us; speedup 1.0000x reference)
//
#include <hip/hip_runtime.h>
#include <cmath>

#define B_ 16
#define N_ 48
#define HID_ 64
#define NL_ 128
#define NNODE_ (B_*N_)        // 768
#define NEDGE_ (B_*N_*N_)     // 36864

__device__ __forceinline__ float sigmoidf_(float x){ return 1.0f/(1.0f+expf(-x)); }

// ---------------------------------------------------------------------------
// K0: A/B column-sums of msg_w2 (3 variants by j%3), bias sums, h_first, mask
// ---------------------------------------------------------------------------
__global__ void k_prep(const float* __restrict__ w2, const float* __restrict__ b2,
                       const float* __restrict__ h0,
                       float* __restrict__ A, float* __restrict__ Bm,
                       float* __restrict__ Ab, float* __restrict__ Bb,
                       float* __restrict__ hfirst, float* __restrict__ mask)
{
    int idx = blockIdx.x*256 + threadIdx.x;
    if (idx < 3*128*64) {
        int r = idx >> 13;          // 0..2
        int c = (idx >> 6) & 127;
        int m = idx & 63;
        int t = 48 - 16*r;
        const float* src = w2 + c*4096 + m*64;
        float a = 0.f, b = 0.f;
        for (int k = 0; k < 64; k++){ float v = src[k]; if (k < t) a += v; else b += v; }
        A[idx] = a; Bm[idx] = b;
    } else if (idx < 3*128*64 + 192) {
        int i2 = idx - 3*128*64;
        int r = i2 >> 6, m = i2 & 63;
        int t = 48 - 16*r;
        const float* src = b2 + m*64;
        float a = 0.f, b = 0.f;
        for (int k = 0; k < 64; k++){ float v = src[k]; if (k < t) a += v; else b += v; }
        Ab[i2] = a; Bb[i2] = b;
    } else {
        int i3 = idx - (3*128*64 + 192);
        if (i3 < NNODE_*HID_) {
            int node = i3 >> 6, m = i3 & 63;
            hfirst[i3] = (m < 32) ? h0[node*32 + m] : 0.f;
            if (m == 0) {
                float s = 0.f;
                for (int k = 0; k < 32; k++) s += h0[node*32 + k];
                mask[node] = (s > 0.f) ? 1.f : 0.f;
            }
        }
    }
}

// ---------------------------------------------------------------------------
// K1: relu2[e,c] = relu(relu(e@w0+b0)@w1+b1), 64 edges per block
// ---------------------------------------------------------------------------
__global__ __launch_bounds__(256) void k_mlp(
    const float* __restrict__ ein, const float* __restrict__ w0, const float* __restrict__ b0,
    const float* __restrict__ w1, const float* __restrict__ b1,
    float* __restrict__ relu2)
{
    __shared__ __align__(16) float w0s[16*128];
    __shared__ __align__(16) float es[64*16];
    __shared__ __align__(16) float x1s[64*128];
    __shared__ float b0s[128], b1s[128];
    int tid = threadIdx.x;
    for (int i = tid; i < 16*128; i += 256) w0s[i] = w0[i];
    if (tid < 128){ b0s[tid] = b0[tid]; b1s[tid] = b1[tid]; }
    int e0 = blockIdx.x * 64;
    for (int i = tid; i < 64*16; i += 256) es[i] = ein[(size_t)e0*16 + i];
    __syncthreads();
    int o = tid & 127, eg = tid >> 7;   // o: output unit, eg: edge-group 0/1
    // layer 1
    for (int eL = eg; eL < 64; eL += 2){
        float acc = b0s[o];
        for (int i = 0; i < 16; i++) acc += es[eL*16 + i] * w0s[i*128 + o];
        x1s[eL*128 + o] = fmaxf(acc, 0.f);
    }
    __syncthreads();
    // layer 2: register-blocked over 32 edges/thread; w1 streamed once/block
    float acc2[32];
    for (int q = 0; q < 32; q++) acc2[q] = b1s[o];
    for (int i4 = 0; i4 < 32; i4++){
        int i = i4 * 4;
        float wv0 = w1[(size_t)(i+0)*128 + o];
        float wv1 = w1[(size_t)(i+1)*128 + o];
        float wv2 = w1[(size_t)(i+2)*128 + o];
        float wv3 = w1[(size_t)(i+3)*128 + o];
        for (int q = 0; q < 32; q++){
            const float4 xv = *(const float4*)&x1s[(eg + q*2)*128 + i];
            acc2[q] += xv.x*wv0 + xv.y*wv1 + xv.z*wv2 + xv.w*wv3;
        }
    }
    for (int q = 0; q < 32; q++){
        int eL = eg + q*2;
        relu2[(size_t)(e0 + eL)*128 + o] = fmaxf(acc2[q], 0.f);
    }
}

// ---------------------------------------------------------------------------
// K2: PA/PB[e,m] = relu2[e,:] @ A_{j%3}[:,m] (+bias sums). Blocks grouped by r.
// ---------------------------------------------------------------------------
__global__ __launch_bounds__(256) void k_papb(
    const float* __restrict__ relu2, const float* __restrict__ A, const float* __restrict__ Bm,
    const float* __restrict__ Ab, const float* __restrict__ Bb,
    float* __restrict__ PA, float* __restrict__ PB)
{
    __shared__ __align__(16) float r2s[32*128];
    __shared__ float Abs[64], Bbs[64];
    __shared__ int eAddr[32];
    int tid = threadIdx.x;
    int r = blockIdx.y;
    int f0 = blockIdx.x * 32;
    if (tid < 64){ Abs[tid] = Ab[r*64 + tid]; Bbs[tid] = Bb[r*64 + tid]; }
    if (tid < 32){
        int f = f0 + tid;
        int bi = f >> 4, tt = f & 15;
        eAddr[tid] = bi*48 + 3*tt + r;
    }
    __syncthreads();
    for (int i = tid; i < 32*128; i += 256){
        int eL = i >> 7, cc = i & 127;
        r2s[i] = relu2[(size_t)eAddr[eL]*128 + cc];
    }
    __syncthreads();
    int m = tid & 63, eg = tid >> 6;    // eg in 0..3, 8 edges per thread
    float pa[8], pb[8];
    for (int q = 0; q < 8; q++){ pa[q] = Abs[m]; pb[q] = Bbs[m]; }
    const float* Ar = A  + r*8192;
    const float* Br = Bm + r*8192;
    for (int c = 0; c < 128; c++){
        float av = Ar[c*64 + m];
        float bv = Br[c*64 + m];
        for (int q = 0; q < 8; q++){
            float v = r2s[(eg + q*4)*128 + c];
            pa[q] += v*av;
            pb[q] += v*bv;
        }
    }
    for (int q = 0; q < 8; q++){
        size_t e = (size_t)eAddr[eg + q*4];
        PA[e*64 + m] = pa[q];
        PB[e*64 + m] = pb[q];
    }
}

// ---------------------------------------------------------------------------
// K3: one message-passing layer + GRU. Block per (b,j), 64 threads (m).
// ---------------------------------------------------------------------------
__global__ __launch_bounds__(64) void k_layer(
    const float* __restrict__ hin, float* __restrict__ hout,
    const float* __restrict__ PA, const float* __restrict__ PB,
    const float* __restrict__ g, const float* __restrict__ mask,
    const float* __restrict__ wih, const float* __restrict__ whh,
    const float* __restrict__ bih, const float* __restrict__ bhh)
{
    int bj = blockIdx.x;
    int b = bj / 48, j = bj - b*48;
    int p0 = j + j/3;                // first h channel used by column j
    int m = threadIdx.x;
    __shared__ float aggs[64], hs[64];
    float agg = 0.f;
    int base = b*48;
    for (int i = 0; i < 48; i++){
        float gv = g[(size_t)(base + i)*48 + j];
        if (gv != 0.f){              // wave-uniform branch
            int node = base + i;
            float ha = hin[node*64 + p0];
            float hb = hin[node*64 + p0 + 1];
            size_t e = (size_t)node*48 + j;
            agg += gv * (ha*PA[e*64 + m] + hb*PB[e*64 + m]);
        }
    }
    aggs[m] = agg;
    hs[m]   = hin[(size_t)bj*64 + m];
    __syncthreads();
    float gir = bih[m], giz = bih[64+m], gin = bih[128+m];
    float ghr = bhh[m], ghz = bhh[64+m], ghn = bhh[128+m];
    const float* wr = wih + m*64;       const float* vr = whh + m*64;
    const float* wz = wih + (64+m)*64;  const float* vz = whh + (64+m)*64;
    const float* wn = wih + (128+m)*64; const float* vn = whh + (128+m)*64;
    for (int k = 0; k < 64; k++){
        float a = aggs[k], h = hs[k];
        gir += a*wr[k]; giz += a*wz[k]; gin += a*wn[k];
        ghr += h*vr[k]; ghz += h*vz[k]; ghn += h*vn[k];
    }
    float rr = sigmoidf_(gir + ghr);
    float zz = sigmoidf_(giz + ghz);
    float nn = tanhf(gin + rr*ghn);
    float hnew = (1.f - zz)*nn + zz*hs[m];
    hout[(size_t)bj*64 + m] = mask[bj] * hnew;
}

// ---------------------------------------------------------------------------
// K4: readout Net0(cat[h_first,hT]) * Net1(hT), partial sums over 4 nodes
// ---------------------------------------------------------------------------
__global__ __launch_bounds__(128) void k_readout(
    const float* __restrict__ hfirst, const float* __restrict__ hT,
    const float* __restrict__ mask,
    const float* __restrict__ w00, const float* __restrict__ b00,
    const float* __restrict__ w01, const float* __restrict__ b01,
    const float* __restrict__ w02, const float* __restrict__ b02,
    const float* __restrict__ w10, const float* __restrict__ b10,
    const float* __restrict__ w11, const float* __restrict__ b11,
    const float* __restrict__ w12, const float* __restrict__ b12,
    float* __restrict__ partial)
{
    int t = threadIdx.x;
    int b = blockIdx.x / 12, c4 = blockIdx.x % 12;
    __shared__ float x0[128], buf1[128], buf2[128];
    float acc = 0.f;
    for (int nl = 0; nl < 4; nl++){
        int node = b*48 + c4*4 + nl;
        if (mask[node] == 0.f) continue;   // block-uniform
        if (t < 64) x0[t] = hfirst[(size_t)node*64 + t];
        else        x0[t] = hT[(size_t)node*64 + (t - 64)];
        __syncthreads();
        float a = b00[t];
        for (int i = 0; i < 128; i++) a += x0[i] * w00[(size_t)i*128 + t];
        buf1[t] = fmaxf(a, 0.f);
        __syncthreads();
        a = b01[t];
        for (int i = 0; i < 128; i++) a += buf1[i] * w01[(size_t)i*128 + t];
        buf2[t] = fmaxf(a, 0.f);
        __syncthreads();
        float o0 = b02[t];
        for (int i = 0; i < 128; i++) o0 += buf2[i] * w02[(size_t)i*128 + t];
        __syncthreads();
        a = b10[t];
        for (int i = 0; i < 64; i++)  a += x0[64 + i] * w10[(size_t)i*128 + t];
        buf1[t] = fmaxf(a, 0.f);
        __syncthreads();
        a = b11[t];
        for (int i = 0; i < 128; i++) a += buf1[i] * w11[(size_t)i*128 + t];
        buf2[t] = fmaxf(a, 0.f);
        __syncthreads();
        float o1 = b12[t];
        for (int i = 0; i < 128; i++) o1 += buf2[i] * w12[(size_t)i*128 + t];
        acc += o0 * o1;
        __syncthreads();
    }
    partial[(size_t)blockIdx.x*128 + t] = acc;
}

// ---------------------------------------------------------------------------
// K5: reduce partials over node-chunks + sigmoid
// ---------------------------------------------------------------------------
__global__ void k_final(const float* __restrict__ partial, float* __restrict__ out)
{
    int idx = blockIdx.x*256 + threadIdx.x;
    if (idx < B_*128){
        int b = idx >> 7, t = idx & 127;
        float s = 0.f;
        for (int c = 0; c < 12; c++) s += partial[(size_t)(b*12 + c)*128 + t];
        out[idx] = 1.0f / (1.0f + expf(-s));
    }
}

// ---------------------------------------------------------------------------
extern "C" void kernel_launch(void* const* d_in, const int* in_sizes, int n_in,
                              void* d_out, int out_size, void* d_ws, size_t ws_size,
                              hipStream_t stream)
{
    (void)in_sizes; (void)n_in; (void)out_size; (void)ws_size;
    const float* g    = (const float*)d_in[0];
    const float* h0   = (const float*)d_in[1];
    const float* e    = (const float*)d_in[2];
    const float* mw0  = (const float*)d_in[3];
    const float* mb0  = (const float*)d_in[4];
    const float* mw1  = (const float*)d_in[5];
    const float* mb1  = (const float*)d_in[6];
    const float* mw2  = (const float*)d_in[7];
    const float* mb2  = (const float*)d_in[8];
    const float* wih  = (const float*)d_in[9];
    const float* whh  = (const float*)d_in[10];
    const float* bih  = (const float*)d_in[11];
    const float* bhh  = (const float*)d_in[12];
    const float* r0w0 = (const float*)d_in[13];
    const float* r0b0 = (const float*)d_in[14];
    const float* r0w1 = (const float*)d_in[15];
    const float* r0b1 = (const float*)d_in[16];
    const float* r0w2 = (const float*)d_in[17];
    const float* r0b2 = (const float*)d_in[18];
    const float* r1w0 = (const float*)d_in[19];
    const float* r1b0 = (const float*)d_in[20];
    const float* r1w1 = (const float*)d_in[21];
    const float* r1b1 = (const float*)d_in[22];
    const float* r1w2 = (const float*)d_in[23];
    const float* r1b2 = (const float*)d_in[24];
    float* out = (float*)d_out;

    float* ws     = (float*)d_ws;
    float* A      = ws;                  // 3*128*64   = 24576
    float* Bm     = A      + 24576;      //              24576
    float* Ab     = Bm     + 24576;      // 3*64       = 192
    float* Bb     = Ab     + 192;        //              192
    float* hfirst = Bb     + 192;        // 768*64     = 49152
    float* hA     = hfirst + 49152;
    float* hB     = hA     + 49152;
    float* mask   = hB     + 49152;      //              768
    float* relu2  = mask   + 768;        // 36864*128  = 4718592
    float* PA     = relu2  + 4718592;    // 36864*64   = 2359296
    float* PB     = PA     + 2359296;    //              2359296
    float* part   = PB     + 2359296;    // 192*128    = 24576
    // total ~ 9.66M floats = 36.9 MiB

    k_prep<<<289, 256, 0, stream>>>(mw2, mb2, h0, A, Bm, Ab, Bb, hfirst, mask);
    k_mlp<<<576, 256, 0, stream>>>(e, mw0, mb0, mw1, mb1, relu2);
    k_papb<<<dim3(384, 3), 256, 0, stream>>>(relu2, A, Bm, Ab, Bb, PA, PB);
    k_layer<<<768, 64, 0, stream>>>(hfirst, hA, PA, PB, g, mask, wih, whh, bih, bhh);
    k_layer<<<768, 64, 0, stream>>>(hA, hB, PA, PB, g, mask, wih, whh, bih, bhh);
    k_layer<<<768, 64, 0, stream>>>(hB, hA, PA, PB, g, mask, wih, whh, bih, bhh);
    k_readout<<<192, 128, 0, stream>>>(hfirst, hA, mask,
                                       r0w0, r0b0, r0w1, r0b1, r0w2, r0b2,
                                       r1w0, r1b0, r1w1, r1b1, r1w2, r1b2, part);
    k_final<<<8, 256, 0, stream>>>(part, out);
}

// Round 2
// 302.426 us; speedup vs baseline: 2.1411x; 2.1411x over previous
//
#include <hip/hip_runtime.h>
#include <cmath>

#define B_ 16
#define N_ 48
#define HID_ 64
#define NL_ 128
#define NNODE_ (B_*N_)        // 768
#define NEDGE_ (B_*N_*N_)     // 36864

__device__ __forceinline__ float sigmoidf_(float x){ return 1.0f/(1.0f+expf(-x)); }

// ---------------------------------------------------------------------------
// K0: A/B column-sums of msg_w2 (3 variants by j%3), bias sums, h_first, mask,
//     and transposed GRU weights (wihT/whhT, [64][192] k-major, coalesced).
// ---------------------------------------------------------------------------
__global__ void k_prep(const float* __restrict__ w2, const float* __restrict__ b2,
                       const float* __restrict__ h0,
                       const float* __restrict__ wih, const float* __restrict__ whh,
                       float* __restrict__ A, float* __restrict__ Bm,
                       float* __restrict__ Ab, float* __restrict__ Bb,
                       float* __restrict__ hfirst, float* __restrict__ mask,
                       float* __restrict__ wihT, float* __restrict__ whhT)
{
    int idx = blockIdx.x*256 + threadIdx.x;
    if (idx < 24576) {
        int r = idx >> 13;          // 0..2
        int c = (idx >> 6) & 127;
        int m = idx & 63;
        int t = 48 - 16*r;
        const float* src = w2 + c*4096 + m*64;
        float a = 0.f, b = 0.f;
        for (int k = 0; k < 64; k++){ float v = src[k]; if (k < t) a += v; else b += v; }
        A[idx] = a; Bm[idx] = b;
    } else if (idx < 24768) {
        int i2 = idx - 24576;
        int r = i2 >> 6, m = i2 & 63;
        int t = 48 - 16*r;
        const float* src = b2 + m*64;
        float a = 0.f, b = 0.f;
        for (int k = 0; k < 64; k++){ float v = src[k]; if (k < t) a += v; else b += v; }
        Ab[i2] = a; Bb[i2] = b;
    } else if (idx < 73920) {
        int i3 = idx - 24768;
        int node = i3 >> 6, m = i3 & 63;
        hfirst[i3] = (m < 32) ? h0[node*32 + m] : 0.f;
        if (m == 0) {
            float s = 0.f;
            for (int k = 0; k < 32; k++) s += h0[node*32 + k];
            mask[node] = (s > 0.f) ? 1.f : 0.f;
        }
    } else if (idx < 98496) {
        int i4 = idx - 73920;
        if (i4 < 12288) {
            int k = i4 / 192, col = i4 - k*192;
            wihT[i4] = wih[col*64 + k];
        } else {
            int i5 = i4 - 12288;
            int k = i5 / 192, col = i5 - k*192;
            whhT[i5] = whh[col*64 + k];
        }
    }
}

// ---------------------------------------------------------------------------
// K1: relu2[e,c] = relu(relu(e@w0+b0)@w1+b1), 64 edges per block
// ---------------------------------------------------------------------------
__global__ __launch_bounds__(256) void k_mlp(
    const float* __restrict__ ein, const float* __restrict__ w0, const float* __restrict__ b0,
    const float* __restrict__ w1, const float* __restrict__ b1,
    float* __restrict__ relu2)
{
    __shared__ __align__(16) float w0s[16*128];
    __shared__ __align__(16) float es[64*16];
    __shared__ __align__(16) float x1s[64*128];
    __shared__ float b0s[128], b1s[128];
    int tid = threadIdx.x;
    for (int i = tid; i < 16*128; i += 256) w0s[i] = w0[i];
    if (tid < 128){ b0s[tid] = b0[tid]; b1s[tid] = b1[tid]; }
    int e0 = blockIdx.x * 64;
    for (int i = tid; i < 64*16; i += 256) es[i] = ein[(size_t)e0*16 + i];
    __syncthreads();
    int o = tid & 127, eg = tid >> 7;   // o: output unit, eg: edge-group 0/1
    // layer 1
    for (int eL = eg; eL < 64; eL += 2){
        float acc = b0s[o];
        for (int i = 0; i < 16; i++) acc += es[eL*16 + i] * w0s[i*128 + o];
        x1s[eL*128 + o] = fmaxf(acc, 0.f);
    }
    __syncthreads();
    // layer 2: register-blocked over 32 edges/thread; w1 streamed once/block
    float acc2[32];
    for (int q = 0; q < 32; q++) acc2[q] = b1s[o];
    for (int i4 = 0; i4 < 32; i4++){
        int i = i4 * 4;
        float wv0 = w1[(size_t)(i+0)*128 + o];
        float wv1 = w1[(size_t)(i+1)*128 + o];
        float wv2 = w1[(size_t)(i+2)*128 + o];
        float wv3 = w1[(size_t)(i+3)*128 + o];
        for (int q = 0; q < 32; q++){
            const float4 xv = *(const float4*)&x1s[(eg + q*2)*128 + i];
            acc2[q] += xv.x*wv0 + xv.y*wv1 + xv.z*wv2 + xv.w*wv3;
        }
    }
    for (int q = 0; q < 32; q++){
        int eL = eg + q*2;
        relu2[(size_t)(e0 + eL)*128 + o] = fmaxf(acc2[q], 0.f);
    }
}

// ---------------------------------------------------------------------------
// K2: PA/PB[e,m] = relu2[e,:] @ A_{j%3}[:,m] (+bias sums). Blocks grouped by r.
// ---------------------------------------------------------------------------
__global__ __launch_bounds__(256) void k_papb(
    const float* __restrict__ relu2, const float* __restrict__ A, const float* __restrict__ Bm,
    const float* __restrict__ Ab, const float* __restrict__ Bb,
    float* __restrict__ PA, float* __restrict__ PB)
{
    __shared__ __align__(16) float r2s[32*128];
    __shared__ float Abs[64], Bbs[64];
    __shared__ int eAddr[32];
    int tid = threadIdx.x;
    int r = blockIdx.y;
    int f0 = blockIdx.x * 32;
    if (tid < 64){ Abs[tid] = Ab[r*64 + tid]; Bbs[tid] = Bb[r*64 + tid]; }
    if (tid < 32){
        int f = f0 + tid;
        int bi = f >> 4, tt = f & 15;
        eAddr[tid] = bi*48 + 3*tt + r;
    }
    __syncthreads();
    for (int i = tid; i < 32*128; i += 256){
        int eL = i >> 7, cc = i & 127;
        r2s[i] = relu2[(size_t)eAddr[eL]*128 + cc];
    }
    __syncthreads();
    int m = tid & 63, eg = tid >> 6;    // eg in 0..3, 8 edges per thread
    float pa[8], pb[8];
    for (int q = 0; q < 8; q++){ pa[q] = Abs[m]; pb[q] = Bbs[m]; }
    const float* Ar = A  + r*8192;
    const float* Br = Bm + r*8192;
    for (int c = 0; c < 128; c++){
        float av = Ar[c*64 + m];
        float bv = Br[c*64 + m];
        for (int q = 0; q < 8; q++){
            float v = r2s[(eg + q*4)*128 + c];
            pa[q] += v*av;
            pb[q] += v*bv;
        }
    }
    for (int q = 0; q < 8; q++){
        size_t e = (size_t)eAddr[eg + q*4];
        PA[e*64 + m] = pa[q];
        PB[e*64 + m] = pb[q];
    }
}

// ---------------------------------------------------------------------------
// K3: one message-passing layer + GRU. Block per (b,j), 256 threads (4 waves).
// Waves split the 48-neighbor loop; GRU gate matvecs use transposed weights.
// ---------------------------------------------------------------------------
__global__ __launch_bounds__(256) void k_layer(
    const float* __restrict__ hin, float* __restrict__ hout,
    const float* __restrict__ PA, const float* __restrict__ PB,
    const float* __restrict__ g, const float* __restrict__ mask,
    const float* __restrict__ wihT, const float* __restrict__ whhT,
    const float* __restrict__ bih, const float* __restrict__ bhh)
{
    int bj = blockIdx.x;
    int b = bj / 48, j = bj - b*48;
    int p0 = j + j/3;                // first h channel used by column j
    int tid = threadIdx.x;
    int w = tid >> 6, m = tid & 63;
    __shared__ float aggp[4][64];
    __shared__ float aggs[64], hs[64];
    __shared__ float gi[192], gh[192];
    if (tid < 64) hs[tid] = hin[(size_t)bj*64 + tid];
    float agg = 0.f;
    int base = b*48;
    for (int ii = 0; ii < 12; ii++){
        int i = w + ii*4;
        int node = base + i;
        float gv = g[(size_t)node*48 + j];
        float ha = hin[node*64 + p0];
        float hb = hin[node*64 + p0 + 1];
        size_t e = (size_t)node*48 + j;
        agg += gv * (ha*PA[e*64 + m] + hb*PB[e*64 + m]);
    }
    aggp[w][m] = agg;
    __syncthreads();
    if (tid < 64) aggs[tid] = aggp[0][tid] + aggp[1][tid] + aggp[2][tid] + aggp[3][tid];
    __syncthreads();
    if (tid < 192){
        float gacc = bih[tid], hacc = bhh[tid];
        for (int k = 0; k < 64; k++){
            gacc += aggs[k] * wihT[k*192 + tid];
            hacc += hs[k]   * whhT[k*192 + tid];
        }
        gi[tid] = gacc; gh[tid] = hacc;
    }
    __syncthreads();
    if (tid < 64){
        float rr = sigmoidf_(gi[tid] + gh[tid]);
        float zz = sigmoidf_(gi[64+tid] + gh[64+tid]);
        float nn = tanhf(gi[128+tid] + rr*gh[128+tid]);
        float hnew = (1.f - zz)*nn + zz*hs[tid];
        hout[(size_t)bj*64 + tid] = mask[bj] * hnew;
    }
}

// ---------------------------------------------------------------------------
// K4: readout, batched. One block per batch b (48 nodes), 256 threads.
// Register-blocked MLP layers through LDS ping-pong; fused mask/sum/sigmoid.
// ---------------------------------------------------------------------------
__device__ __forceinline__ void mlp_layer_(
    const float* __restrict__ Xs,      // LDS input, row stride 128
    const float* __restrict__ W,       // global [dim][128]
    const float* __restrict__ bias,    // global [128]
    float* __restrict__ Ys,            // LDS output, row stride 128
    int dim, int o, int eg, bool do_relu)
{
    float acc[24];
    float bo = bias[o];
    for (int q = 0; q < 24; q++) acc[q] = bo;
    for (int i = 0; i < dim; i += 4){
        float w0 = W[(size_t)(i+0)*128 + o];
        float w1 = W[(size_t)(i+1)*128 + o];
        float w2 = W[(size_t)(i+2)*128 + o];
        float w3 = W[(size_t)(i+3)*128 + o];
        for (int q = 0; q < 24; q++){
            const float4 xv = *(const float4*)&Xs[(eg + q*2)*128 + i];
            acc[q] += xv.x*w0 + xv.y*w1 + xv.z*w2 + xv.w*w3;
        }
    }
    for (int q = 0; q < 24; q++){
        float v = do_relu ? fmaxf(acc[q], 0.f) : acc[q];
        Ys[(eg + q*2)*128 + o] = v;
    }
}

__global__ __launch_bounds__(256) void k_read(
    const float* __restrict__ hfirst, const float* __restrict__ hT,
    const float* __restrict__ mask,
    const float* __restrict__ w00, const float* __restrict__ b00,
    const float* __restrict__ w01, const float* __restrict__ b01,
    const float* __restrict__ w02, const float* __restrict__ b02,
    const float* __restrict__ w10, const float* __restrict__ b10,
    const float* __restrict__ w11, const float* __restrict__ b11,
    const float* __restrict__ w12, const float* __restrict__ b12,
    float* __restrict__ out)
{
    __shared__ __align__(16) float bufA[48*128];
    __shared__ __align__(16) float bufB[48*128];
    __shared__ __align__(16) float bufC[48*128];
    __shared__ float maskS[48];
    int tid = threadIdx.x;
    int b = blockIdx.x;
    int o = tid & 127, eg = tid >> 7;
    if (tid < 48) maskS[tid] = mask[b*48 + tid];
    for (int i = tid; i < 48*128; i += 256){
        int r = i >> 7, c = i & 127;
        int node = b*48 + r;
        bufA[i] = (c < 64) ? hfirst[(size_t)node*64 + c]
                           : hT[(size_t)node*64 + (c - 64)];
    }
    __syncthreads();
    // Net0
    mlp_layer_(bufA,      w00, b00, bufB, 128, o, eg, true);   __syncthreads();
    mlp_layer_(bufB,      w01, b01, bufC, 128, o, eg, true);   __syncthreads();
    mlp_layer_(bufC,      w02, b02, bufB, 128, o, eg, false);  __syncthreads();  // bufB = o0
    // Net1 (input = bufA[:,64:128])
    mlp_layer_(bufA + 64, w10, b10, bufC, 64,  o, eg, true);   __syncthreads();
    mlp_layer_(bufC,      w11, b11, bufA, 128, o, eg, true);   __syncthreads();
    // last layer of Net1 in regs, fused with o0 * o1 masked node-sum
    {
        float acc[24];
        float bo = b12[o];
        for (int q = 0; q < 24; q++) acc[q] = bo;
        for (int i = 0; i < 128; i += 4){
            float w0 = w12[(size_t)(i+0)*128 + o];
            float w1 = w12[(size_t)(i+1)*128 + o];
            float w2 = w12[(size_t)(i+2)*128 + o];
            float w3 = w12[(size_t)(i+3)*128 + o];
            for (int q = 0; q < 24; q++){
                const float4 xv = *(const float4*)&bufA[(eg + q*2)*128 + i];
                acc[q] += xv.x*w0 + xv.y*w1 + xv.z*w2 + xv.w*w3;
            }
        }
        float s = 0.f;
        for (int q = 0; q < 24; q++){
            int r = eg + q*2;
            s += maskS[r] * bufB[r*128 + o] * acc[q];
        }
        __syncthreads();
        bufC[eg*128 + o] = s;
    }
    __syncthreads();
    if (tid < 128)
        out[(size_t)b*128 + tid] = 1.0f / (1.0f + expf(-(bufC[tid] + bufC[128 + tid])));
}

// ---------------------------------------------------------------------------
extern "C" void kernel_launch(void* const* d_in, const int* in_sizes, int n_in,
                              void* d_out, int out_size, void* d_ws, size_t ws_size,
                              hipStream_t stream)
{
    (void)in_sizes; (void)n_in; (void)out_size; (void)ws_size;
    const float* g    = (const float*)d_in[0];
    const float* h0   = (const float*)d_in[1];
    const float* e    = (const float*)d_in[2];
    const float* mw0  = (const float*)d_in[3];
    const float* mb0  = (const float*)d_in[4];
    const float* mw1  = (const float*)d_in[5];
    const float* mb1  = (const float*)d_in[6];
    const float* mw2  = (const float*)d_in[7];
    const float* mb2  = (const float*)d_in[8];
    const float* wih  = (const float*)d_in[9];
    const float* whh  = (const float*)d_in[10];
    const float* bih  = (const float*)d_in[11];
    const float* bhh  = (const float*)d_in[12];
    const float* r0w0 = (const float*)d_in[13];
    const float* r0b0 = (const float*)d_in[14];
    const float* r0w1 = (const float*)d_in[15];
    const float* r0b1 = (const float*)d_in[16];
    const float* r0w2 = (const float*)d_in[17];
    const float* r0b2 = (const float*)d_in[18];
    const float* r1w0 = (const float*)d_in[19];
    const float* r1b0 = (const float*)d_in[20];
    const float* r1w1 = (const float*)d_in[21];
    const float* r1b1 = (const float*)d_in[22];
    const float* r1w2 = (const float*)d_in[23];
    const float* r1b2 = (const float*)d_in[24];
    float* out = (float*)d_out;

    float* ws     = (float*)d_ws;
    float* A      = ws;                  // 3*128*64   = 24576
    float* Bm     = A      + 24576;      //              24576
    float* Ab     = Bm     + 24576;      // 3*64       = 192
    float* Bb     = Ab     + 192;        //              192
    float* hfirst = Bb     + 192;        // 768*64     = 49152
    float* hA     = hfirst + 49152;
    float* hB     = hA     + 49152;
    float* mask   = hB     + 49152;      //              768
    float* wihT   = mask   + 768;        // 64*192     = 12288
    float* whhT   = wihT   + 12288;      //              12288
    float* relu2  = whhT   + 12288;      // 36864*128  = 4718592
    float* PA     = relu2  + 4718592;    // 36864*64   = 2359296
    float* PB     = PA     + 2359296;    //              2359296
    // total ~ 9.66M floats = 36.9 MiB

    k_prep<<<385, 256, 0, stream>>>(mw2, mb2, h0, wih, whh,
                                    A, Bm, Ab, Bb, hfirst, mask, wihT, whhT);
    k_mlp<<<576, 256, 0, stream>>>(e, mw0, mb0, mw1, mb1, relu2);
    k_papb<<<dim3(384, 3), 256, 0, stream>>>(relu2, A, Bm, Ab, Bb, PA, PB);
    k_layer<<<768, 256, 0, stream>>>(hfirst, hA, PA, PB, g, mask, wihT, whhT, bih, bhh);
    k_layer<<<768, 256, 0, stream>>>(hA, hB, PA, PB, g, mask, wihT, whhT, bih, bhh);
    k_layer<<<768, 256, 0, stream>>>(hB, hA, PA, PB, g, mask, wihT, whhT, bih, bhh);
    k_read<<<16, 256, 0, stream>>>(hfirst, hA, mask,
                                   r0w0, r0b0, r0w1, r0b1, r0w2, r0b2,
                                   r1w0, r1b0, r1w1, r1b1, r1w2, r1b2, out);
}

// Round 3
// 246.496 us; speedup vs baseline: 2.6270x; 1.2269x over previous
//
#include <hip/hip_runtime.h>
#include <cmath>

#define B_ 16
#define N_ 48
#define HID_ 64
#define NL_ 128
#define NNODE_ (B_*N_)        // 768
#define NEDGE_ (B_*N_*N_)     // 36864

__device__ __forceinline__ float sigmoidf_(float x){ return 1.0f/(1.0f+expf(-x)); }

// ---------------------------------------------------------------------------
// K0: A/B column-sums of msg_w2 (3 variants by j%3), bias sums, h_first, mask,
//     and transposed GRU weights (wihT/whhT, [64][192] k-major, coalesced).
// ---------------------------------------------------------------------------
__global__ void k_prep(const float* __restrict__ w2, const float* __restrict__ b2,
                       const float* __restrict__ h0,
                       const float* __restrict__ wih, const float* __restrict__ whh,
                       float* __restrict__ A, float* __restrict__ Bm,
                       float* __restrict__ Ab, float* __restrict__ Bb,
                       float* __restrict__ hfirst, float* __restrict__ mask,
                       float* __restrict__ wihT, float* __restrict__ whhT)
{
    int idx = blockIdx.x*256 + threadIdx.x;
    if (idx < 24576) {
        int r = idx >> 13;          // 0..2
        int c = (idx >> 6) & 127;
        int m = idx & 63;
        int t = 48 - 16*r;
        const float* src = w2 + c*4096 + m*64;
        float a = 0.f, b = 0.f;
        for (int k = 0; k < 64; k++){ float v = src[k]; if (k < t) a += v; else b += v; }
        A[idx] = a; Bm[idx] = b;
    } else if (idx < 24768) {
        int i2 = idx - 24576;
        int r = i2 >> 6, m = i2 & 63;
        int t = 48 - 16*r;
        const float* src = b2 + m*64;
        float a = 0.f, b = 0.f;
        for (int k = 0; k < 64; k++){ float v = src[k]; if (k < t) a += v; else b += v; }
        Ab[i2] = a; Bb[i2] = b;
    } else if (idx < 73920) {
        int i3 = idx - 24768;
        int node = i3 >> 6, m = i3 & 63;
        hfirst[i3] = (m < 32) ? h0[node*32 + m] : 0.f;
        if (m == 0) {
            float s = 0.f;
            for (int k = 0; k < 32; k++) s += h0[node*32 + k];
            mask[node] = (s > 0.f) ? 1.f : 0.f;
        }
    } else if (idx < 98496) {
        int i4 = idx - 73920;
        if (i4 < 12288) {
            int k = i4 / 192, col = i4 - k*192;
            wihT[i4] = wih[col*64 + k];
        } else {
            int i5 = i4 - 12288;
            int k = i5 / 192, col = i5 - k*192;
            whhT[i5] = whh[col*64 + k];
        }
    }
}

// ---------------------------------------------------------------------------
// K1: relu2[e,c] = relu(relu(e@w0+b0)@w1+b1), 64 edges per block
// ---------------------------------------------------------------------------
__global__ __launch_bounds__(256) void k_mlp(
    const float* __restrict__ ein, const float* __restrict__ w0, const float* __restrict__ b0,
    const float* __restrict__ w1, const float* __restrict__ b1,
    float* __restrict__ relu2)
{
    __shared__ __align__(16) float w0s[16*128];
    __shared__ __align__(16) float es[64*16];
    __shared__ __align__(16) float x1s[64*128];
    __shared__ float b0s[128], b1s[128];
    int tid = threadIdx.x;
    for (int i = tid; i < 16*128; i += 256) w0s[i] = w0[i];
    if (tid < 128){ b0s[tid] = b0[tid]; b1s[tid] = b1[tid]; }
    int e0 = blockIdx.x * 64;
    for (int i = tid; i < 64*16; i += 256) es[i] = ein[(size_t)e0*16 + i];
    __syncthreads();
    int o = tid & 127, eg = tid >> 7;   // o: output unit, eg: edge-group 0/1
    // layer 1
    for (int eL = eg; eL < 64; eL += 2){
        float acc = b0s[o];
        for (int i = 0; i < 16; i++) acc += es[eL*16 + i] * w0s[i*128 + o];
        x1s[eL*128 + o] = fmaxf(acc, 0.f);
    }
    __syncthreads();
    // layer 2: register-blocked over 32 edges/thread; w1 streamed once/block
    float acc2[32];
    for (int q = 0; q < 32; q++) acc2[q] = b1s[o];
    for (int i4 = 0; i4 < 32; i4++){
        int i = i4 * 4;
        float wv0 = w1[(size_t)(i+0)*128 + o];
        float wv1 = w1[(size_t)(i+1)*128 + o];
        float wv2 = w1[(size_t)(i+2)*128 + o];
        float wv3 = w1[(size_t)(i+3)*128 + o];
        for (int q = 0; q < 32; q++){
            const float4 xv = *(const float4*)&x1s[(eg + q*2)*128 + i];
            acc2[q] += xv.x*wv0 + xv.y*wv1 + xv.z*wv2 + xv.w*wv3;
        }
    }
    for (int q = 0; q < 32; q++){
        int eL = eg + q*2;
        relu2[(size_t)(e0 + eL)*128 + o] = fmaxf(acc2[q], 0.f);
    }
}

// ---------------------------------------------------------------------------
// K2: PA/PB[e,m] = relu2[e,:] @ A_{j%3}[:,m] (+bias sums). Blocks grouped by r.
// ---------------------------------------------------------------------------
__global__ __launch_bounds__(256) void k_papb(
    const float* __restrict__ relu2, const float* __restrict__ A, const float* __restrict__ Bm,
    const float* __restrict__ Ab, const float* __restrict__ Bb,
    float* __restrict__ PA, float* __restrict__ PB)
{
    __shared__ __align__(16) float r2s[32*128];
    __shared__ float Abs[64], Bbs[64];
    __shared__ int eAddr[32];
    int tid = threadIdx.x;
    int r = blockIdx.y;
    int f0 = blockIdx.x * 32;
    if (tid < 64){ Abs[tid] = Ab[r*64 + tid]; Bbs[tid] = Bb[r*64 + tid]; }
    if (tid < 32){
        int f = f0 + tid;
        int bi = f >> 4, tt = f & 15;
        eAddr[tid] = bi*48 + 3*tt + r;
    }
    __syncthreads();
    for (int i = tid; i < 32*128; i += 256){
        int eL = i >> 7, cc = i & 127;
        r2s[i] = relu2[(size_t)eAddr[eL]*128 + cc];
    }
    __syncthreads();
    int m = tid & 63, eg = tid >> 6;    // eg in 0..3, 8 edges per thread
    float pa[8], pb[8];
    for (int q = 0; q < 8; q++){ pa[q] = Abs[m]; pb[q] = Bbs[m]; }
    const float* Ar = A  + r*8192;
    const float* Br = Bm + r*8192;
    for (int c = 0; c < 128; c++){
        float av = Ar[c*64 + m];
        float bv = Br[c*64 + m];
        for (int q = 0; q < 8; q++){
            float v = r2s[(eg + q*4)*128 + c];
            pa[q] += v*av;
            pb[q] += v*bv;
        }
    }
    for (int q = 0; q < 8; q++){
        size_t e = (size_t)eAddr[eg + q*4];
        PA[e*64 + m] = pa[q];
        PB[e*64 + m] = pb[q];
    }
}

// ---------------------------------------------------------------------------
// K3: one message-passing layer + GRU. Block per (b,j), 256 threads (4 waves).
// ---------------------------------------------------------------------------
__global__ __launch_bounds__(256) void k_layer(
    const float* __restrict__ hin, float* __restrict__ hout,
    const float* __restrict__ PA, const float* __restrict__ PB,
    const float* __restrict__ g, const float* __restrict__ mask,
    const float* __restrict__ wihT, const float* __restrict__ whhT,
    const float* __restrict__ bih, const float* __restrict__ bhh)
{
    int bj = blockIdx.x;
    int b = bj / 48, j = bj - b*48;
    int p0 = j + j/3;                // first h channel used by column j
    int tid = threadIdx.x;
    int w = tid >> 6, m = tid & 63;
    __shared__ float aggp[4][64];
    __shared__ float aggs[64], hs[64];
    __shared__ float gi[192], gh[192];
    if (tid < 64) hs[tid] = hin[(size_t)bj*64 + tid];
    float agg = 0.f;
    int base = b*48;
    for (int ii = 0; ii < 12; ii++){
        int i = w + ii*4;
        int node = base + i;
        float gv = g[(size_t)node*48 + j];
        float ha = hin[node*64 + p0];
        float hb = hin[node*64 + p0 + 1];
        size_t e = (size_t)node*48 + j;
        agg += gv * (ha*PA[e*64 + m] + hb*PB[e*64 + m]);
    }
    aggp[w][m] = agg;
    __syncthreads();
    if (tid < 64) aggs[tid] = aggp[0][tid] + aggp[1][tid] + aggp[2][tid] + aggp[3][tid];
    __syncthreads();
    if (tid < 192){
        float gacc = bih[tid], hacc = bhh[tid];
        for (int k = 0; k < 64; k++){
            gacc += aggs[k] * wihT[k*192 + tid];
            hacc += hs[k]   * whhT[k*192 + tid];
        }
        gi[tid] = gacc; gh[tid] = hacc;
    }
    __syncthreads();
    if (tid < 64){
        float rr = sigmoidf_(gi[tid] + gh[tid]);
        float zz = sigmoidf_(gi[64+tid] + gh[64+tid]);
        float nn = tanhf(gi[128+tid] + rr*gh[128+tid]);
        float hnew = (1.f - zz)*nn + zz*hs[tid];
        hout[(size_t)bj*64 + tid] = mask[bj] * hnew;
    }
}

// ---------------------------------------------------------------------------
// K4: readout, 192 blocks (16 batches x 12 groups of 4 nodes), 256 threads.
// Thread owns (out unit o, node-pair ng); 2 accumulators; weights streamed.
// ---------------------------------------------------------------------------
__device__ __forceinline__ void rd_layer(
    const float* __restrict__ Xs,      // LDS input, row stride 128
    const float* __restrict__ W,       // global [dim][128]
    const float* __restrict__ bias,    // global [128]
    float* __restrict__ Ys,            // LDS output, row stride 128
    int dim, int o, int ng, bool do_relu)
{
    float a0 = bias[o];
    float a1 = a0;
    for (int i = 0; i < dim; i += 4){
        float w0 = W[(size_t)(i+0)*128 + o];
        float w1 = W[(size_t)(i+1)*128 + o];
        float w2 = W[(size_t)(i+2)*128 + o];
        float w3 = W[(size_t)(i+3)*128 + o];
        const float4 x0 = *(const float4*)&Xs[ng*128 + i];        // wave-broadcast
        const float4 x1 = *(const float4*)&Xs[(ng+2)*128 + i];
        a0 += x0.x*w0 + x0.y*w1 + x0.z*w2 + x0.w*w3;
        a1 += x1.x*w0 + x1.y*w1 + x1.z*w2 + x1.w*w3;
    }
    if (do_relu){ a0 = fmaxf(a0, 0.f); a1 = fmaxf(a1, 0.f); }
    Ys[ng*128 + o] = a0;
    Ys[(ng+2)*128 + o] = a1;
}

__global__ __launch_bounds__(256) void k_read(
    const float* __restrict__ hfirst, const float* __restrict__ hT,
    const float* __restrict__ mask,
    const float* __restrict__ w00, const float* __restrict__ b00,
    const float* __restrict__ w01, const float* __restrict__ b01,
    const float* __restrict__ w02, const float* __restrict__ b02,
    const float* __restrict__ w10, const float* __restrict__ b10,
    const float* __restrict__ w11, const float* __restrict__ b11,
    const float* __restrict__ w12, const float* __restrict__ b12,
    float* __restrict__ partial)
{
    __shared__ __align__(16) float xs[4*128];
    __shared__ __align__(16) float ys[4*128];
    __shared__ __align__(16) float zs[4*128];
    __shared__ __align__(16) float os0[4*128];
    __shared__ float mS[4];
    int tid = threadIdx.x;
    int b = blockIdx.x / 12, gg = blockIdx.x - b*12;
    int node0 = b*48 + gg*4;
    int o = tid & 127, ng = tid >> 7;   // ng 0/1; thread handles nodes ng, ng+2
    if (tid < 4) mS[tid] = mask[node0 + tid];
    for (int i = tid; i < 4*128; i += 256){
        int r = i >> 7, c = i & 127;
        xs[i] = (c < 64) ? hfirst[(size_t)(node0+r)*64 + c]
                         : hT[(size_t)(node0+r)*64 + (c - 64)];
    }
    __syncthreads();
    // Net0
    rd_layer(xs,      w00, b00, ys,  128, o, ng, true);  __syncthreads();
    rd_layer(ys,      w01, b01, zs,  128, o, ng, true);  __syncthreads();
    rd_layer(zs,      w02, b02, os0, 128, o, ng, false); __syncthreads();
    // Net1 (input = xs[:,64:128], row stride still 128)
    rd_layer(xs + 64, w10, b10, ys,  64,  o, ng, true);  __syncthreads();
    rd_layer(ys,      w11, b11, zs,  128, o, ng, true);  __syncthreads();
    // last Net1 layer in regs, fused with mask * o0 * o1 and node reduction
    {
        float a0 = b12[o];
        float a1 = a0;
        for (int i = 0; i < 128; i += 4){
            float w0 = w12[(size_t)(i+0)*128 + o];
            float w1 = w12[(size_t)(i+1)*128 + o];
            float w2 = w12[(size_t)(i+2)*128 + o];
            float w3 = w12[(size_t)(i+3)*128 + o];
            const float4 x0 = *(const float4*)&zs[ng*128 + i];
            const float4 x1 = *(const float4*)&zs[(ng+2)*128 + i];
            a0 += x0.x*w0 + x0.y*w1 + x0.z*w2 + x0.w*w3;
            a1 += x1.x*w0 + x1.y*w1 + x1.z*w2 + x1.w*w3;
        }
        float s = mS[ng]   * os0[ng*128 + o]     * a0
                + mS[ng+2] * os0[(ng+2)*128 + o] * a1;
        __syncthreads();
        ys[ng*128 + o] = s;
    }
    __syncthreads();
    if (tid < 128)
        partial[(size_t)blockIdx.x*128 + tid] = ys[tid] + ys[128 + tid];
}

// ---------------------------------------------------------------------------
// K5: reduce 12 partials per batch + sigmoid
// ---------------------------------------------------------------------------
__global__ void k_final(const float* __restrict__ partial, float* __restrict__ out)
{
    int idx = blockIdx.x*256 + threadIdx.x;
    if (idx < B_*128){
        int b = idx >> 7, t = idx & 127;
        float s = 0.f;
        for (int c = 0; c < 12; c++) s += partial[(size_t)(b*12 + c)*128 + t];
        out[idx] = 1.0f / (1.0f + expf(-s));
    }
}

// ---------------------------------------------------------------------------
extern "C" void kernel_launch(void* const* d_in, const int* in_sizes, int n_in,
                              void* d_out, int out_size, void* d_ws, size_t ws_size,
                              hipStream_t stream)
{
    (void)in_sizes; (void)n_in; (void)out_size; (void)ws_size;
    const float* g    = (const float*)d_in[0];
    const float* h0   = (const float*)d_in[1];
    const float* e    = (const float*)d_in[2];
    const float* mw0  = (const float*)d_in[3];
    const float* mb0  = (const float*)d_in[4];
    const float* mw1  = (const float*)d_in[5];
    const float* mb1  = (const float*)d_in[6];
    const float* mw2  = (const float*)d_in[7];
    const float* mb2  = (const float*)d_in[8];
    const float* wih  = (const float*)d_in[9];
    const float* whh  = (const float*)d_in[10];
    const float* bih  = (const float*)d_in[11];
    const float* bhh  = (const float*)d_in[12];
    const float* r0w0 = (const float*)d_in[13];
    const float* r0b0 = (const float*)d_in[14];
    const float* r0w1 = (const float*)d_in[15];
    const float* r0b1 = (const float*)d_in[16];
    const float* r0w2 = (const float*)d_in[17];
    const float* r0b2 = (const float*)d_in[18];
    const float* r1w0 = (const float*)d_in[19];
    const float* r1b0 = (const float*)d_in[20];
    const float* r1w1 = (const float*)d_in[21];
    const float* r1b1 = (const float*)d_in[22];
    const float* r1w2 = (const float*)d_in[23];
    const float* r1b2 = (const float*)d_in[24];
    float* out = (float*)d_out;

    float* ws     = (float*)d_ws;
    float* A      = ws;                  // 3*128*64   = 24576
    float* Bm     = A      + 24576;      //              24576
    float* Ab     = Bm     + 24576;      // 3*64       = 192
    float* Bb     = Ab     + 192;        //              192
    float* hfirst = Bb     + 192;        // 768*64     = 49152
    float* hA     = hfirst + 49152;
    float* hB     = hA     + 49152;
    float* mask   = hB     + 49152;      //              768
    float* wihT   = mask   + 768;        // 64*192     = 12288
    float* whhT   = wihT   + 12288;      //              12288
    float* part   = whhT   + 12288;      // 192*128    = 24576
    float* relu2  = part   + 24576;      // 36864*128  = 4718592
    float* PA     = relu2  + 4718592;    // 36864*64   = 2359296
    float* PB     = PA     + 2359296;    //              2359296
    // total ~ 9.7M floats = 37 MiB

    k_prep<<<385, 256, 0, stream>>>(mw2, mb2, h0, wih, whh,
                                    A, Bm, Ab, Bb, hfirst, mask, wihT, whhT);
    k_mlp<<<576, 256, 0, stream>>>(e, mw0, mb0, mw1, mb1, relu2);
    k_papb<<<dim3(384, 3), 256, 0, stream>>>(relu2, A, Bm, Ab, Bb, PA, PB);
    k_layer<<<768, 256, 0, stream>>>(hfirst, hA, PA, PB, g, mask, wihT, whhT, bih, bhh);
    k_layer<<<768, 256, 0, stream>>>(hA, hB, PA, PB, g, mask, wihT, whhT, bih, bhh);
    k_layer<<<768, 256, 0, stream>>>(hB, hA, PA, PB, g, mask, wihT, whhT, bih, bhh);
    k_read<<<192, 256, 0, stream>>>(hfirst, hA, mask,
                                    r0w0, r0b0, r0w1, r0b1, r0w2, r0b2,
                                    r1w0, r1b0, r1w1, r1b1, r1w2, r1b2, part);
    k_final<<<8, 256, 0, stream>>>(part, out);
}

// Round 4
// 193.632 us; speedup vs baseline: 3.3442x; 1.2730x over previous
//
#include <hip/hip_runtime.h>
#include <cmath>

#define B_ 16
#define N_ 48
#define HID_ 64
#define NL_ 128
#define NNODE_ (B_*N_)        // 768
#define NEDGE_ (B_*N_*N_)     // 36864

__device__ __forceinline__ float sigmoidf_(float x){ return 1.0f/(1.0f+expf(-x)); }

// ---------------------------------------------------------------------------
// K0: A/B column-sums of msg_w2 (3 variants by j%3), bias sums, h_first, mask,
//     transposed GRU weights (wihT/whhT [64][192]), transposed w1T [128][128].
// ---------------------------------------------------------------------------
__global__ void k_prep(const float* __restrict__ w2, const float* __restrict__ b2,
                       const float* __restrict__ h0,
                       const float* __restrict__ wih, const float* __restrict__ whh,
                       const float* __restrict__ w1,
                       float* __restrict__ A, float* __restrict__ Bm,
                       float* __restrict__ Ab, float* __restrict__ Bb,
                       float* __restrict__ hfirst, float* __restrict__ mask,
                       float* __restrict__ wihT, float* __restrict__ whhT,
                       float* __restrict__ w1T)
{
    int idx = blockIdx.x*256 + threadIdx.x;
    if (idx < 24576) {
        int r = idx >> 13;          // 0..2
        int c = (idx >> 6) & 127;
        int m = idx & 63;
        int t = 48 - 16*r;
        const float* src = w2 + c*4096 + m*64;
        float a = 0.f, b = 0.f;
        for (int k = 0; k < 64; k++){ float v = src[k]; if (k < t) a += v; else b += v; }
        A[idx] = a; Bm[idx] = b;
    } else if (idx < 24768) {
        int i2 = idx - 24576;
        int r = i2 >> 6, m = i2 & 63;
        int t = 48 - 16*r;
        const float* src = b2 + m*64;
        float a = 0.f, b = 0.f;
        for (int k = 0; k < 64; k++){ float v = src[k]; if (k < t) a += v; else b += v; }
        Ab[i2] = a; Bb[i2] = b;
    } else if (idx < 73920) {
        int i3 = idx - 24768;
        int node = i3 >> 6, m = i3 & 63;
        hfirst[i3] = (m < 32) ? h0[node*32 + m] : 0.f;
        if (m == 0) {
            float s = 0.f;
            for (int k = 0; k < 32; k++) s += h0[node*32 + k];
            mask[node] = (s > 0.f) ? 1.f : 0.f;
        }
    } else if (idx < 98496) {
        int i4 = idx - 73920;
        if (i4 < 12288) {
            int k = i4 / 192, col = i4 - k*192;
            wihT[i4] = wih[col*64 + k];
        } else {
            int i5 = i4 - 12288;
            int k = i5 / 192, col = i5 - k*192;
            whhT[i5] = whh[col*64 + k];
        }
    } else if (idx < 114880) {
        int i6 = idx - 98496;
        int o = i6 >> 7, i = i6 & 127;
        w1T[i6] = w1[i*128 + o];
    }
}

// ---------------------------------------------------------------------------
// K1: relu2[e,c] = relu(relu(e@w0+b0)@w1+b1), 64 edges per block.
// Thread owns 4 edges x 8 outputs in registers; x1 staged in LDS (stride 132,
// 2-way bank aliasing = free); weights streamed from global (L1/L2).
// ---------------------------------------------------------------------------
__global__ __launch_bounds__(256) void k_mlp(
    const float* __restrict__ ein, const float* __restrict__ w0, const float* __restrict__ b0,
    const float* __restrict__ w1T, const float* __restrict__ b1,
    float* __restrict__ relu2)
{
    __shared__ __align__(16) float x1s[64*132];
    int tid = threadIdx.x;
    int et = tid & 15, ot = tid >> 4;
    int o0 = ot * 8;
    size_t e0 = (size_t)blockIdx.x * 64;

    // ---- layer 1 ----
    float acc[4][8];
    {
        float4 ba = *(const float4*)&b0[o0];
        float4 bb = *(const float4*)&b0[o0 + 4];
        #pragma unroll
        for (int q = 0; q < 4; q++){
            acc[q][0]=ba.x; acc[q][1]=ba.y; acc[q][2]=ba.z; acc[q][3]=ba.w;
            acc[q][4]=bb.x; acc[q][5]=bb.y; acc[q][6]=bb.z; acc[q][7]=bb.w;
        }
    }
    #pragma unroll
    for (int i4 = 0; i4 < 4; i4++){
        float4 ev[4];
        #pragma unroll
        for (int q = 0; q < 4; q++)
            ev[q] = *(const float4*)&ein[(e0 + q*16 + et)*16 + i4*4];
        #pragma unroll
        for (int d = 0; d < 4; d++){
            int i = i4*4 + d;
            float4 wa = *(const float4*)&w0[i*128 + o0];
            float4 wb = *(const float4*)&w0[i*128 + o0 + 4];
            #pragma unroll
            for (int q = 0; q < 4; q++){
                float xi = (d==0) ? ev[q].x : (d==1) ? ev[q].y : (d==2) ? ev[q].z : ev[q].w;
                acc[q][0] += xi*wa.x; acc[q][1] += xi*wa.y;
                acc[q][2] += xi*wa.z; acc[q][3] += xi*wa.w;
                acc[q][4] += xi*wb.x; acc[q][5] += xi*wb.y;
                acc[q][6] += xi*wb.z; acc[q][7] += xi*wb.w;
            }
        }
    }
    #pragma unroll
    for (int q = 0; q < 4; q++){
        int e = q*16 + et;
        float4 s0 = make_float4(fmaxf(acc[q][0],0.f), fmaxf(acc[q][1],0.f),
                                fmaxf(acc[q][2],0.f), fmaxf(acc[q][3],0.f));
        float4 s1 = make_float4(fmaxf(acc[q][4],0.f), fmaxf(acc[q][5],0.f),
                                fmaxf(acc[q][6],0.f), fmaxf(acc[q][7],0.f));
        *(float4*)&x1s[e*132 + o0]     = s0;
        *(float4*)&x1s[e*132 + o0 + 4] = s1;
    }
    __syncthreads();

    // ---- layer 2 ----
    float a2[4][8];
    {
        float4 ba = *(const float4*)&b1[o0];
        float4 bb = *(const float4*)&b1[o0 + 4];
        #pragma unroll
        for (int q = 0; q < 4; q++){
            a2[q][0]=ba.x; a2[q][1]=ba.y; a2[q][2]=ba.z; a2[q][3]=ba.w;
            a2[q][4]=bb.x; a2[q][5]=bb.y; a2[q][6]=bb.z; a2[q][7]=bb.w;
        }
    }
    for (int i4 = 0; i4 < 32; i4++){
        int i = i4*4;
        float4 wv[8];
        #pragma unroll
        for (int r2 = 0; r2 < 8; r2++)
            wv[r2] = *(const float4*)&w1T[(size_t)(o0 + r2)*128 + i];
        #pragma unroll
        for (int q = 0; q < 4; q++){
            float4 xv = *(const float4*)&x1s[(q*16 + et)*132 + i];
            #pragma unroll
            for (int r2 = 0; r2 < 8; r2++){
                a2[q][r2] += xv.x*wv[r2].x + xv.y*wv[r2].y
                           + xv.z*wv[r2].z + xv.w*wv[r2].w;
            }
        }
    }
    #pragma unroll
    for (int q = 0; q < 4; q++){
        size_t e = e0 + q*16 + et;
        float4 s0 = make_float4(fmaxf(a2[q][0],0.f), fmaxf(a2[q][1],0.f),
                                fmaxf(a2[q][2],0.f), fmaxf(a2[q][3],0.f));
        float4 s1 = make_float4(fmaxf(a2[q][4],0.f), fmaxf(a2[q][5],0.f),
                                fmaxf(a2[q][6],0.f), fmaxf(a2[q][7],0.f));
        *(float4*)&relu2[e*128 + o0]     = s0;
        *(float4*)&relu2[e*128 + o0 + 4] = s1;
    }
}

// ---------------------------------------------------------------------------
// K3: one message-passing layer + GRU via U/V contraction (no PA/PB):
// agg[m] = sum_c U[c]A[r,c,m] + V[c]B[r,c,m] + sA*Ab[r,m] + sB*Bb[r,m]
// U[c] = sum_i g*ha*relu2[e(i),c],  V with hb.  Block per (b,j), 256 thr.
// ---------------------------------------------------------------------------
__global__ __launch_bounds__(256) void k_layer(
    const float* __restrict__ hin, float* __restrict__ hout,
    const float* __restrict__ relu2,
    const float* __restrict__ A, const float* __restrict__ Bm,
    const float* __restrict__ Ab, const float* __restrict__ Bb,
    const float* __restrict__ g, const float* __restrict__ mask,
    const float* __restrict__ wihT, const float* __restrict__ whhT,
    const float* __restrict__ bih, const float* __restrict__ bhh)
{
    int bj = blockIdx.x;
    int b = bj / 48, j = bj - b*48;
    int r = j % 3;
    int p0 = j + j/3;
    int tid = threadIdx.x;
    int base = b*48;
    __shared__ float hs[64], wAs[48], wBs[48];
    __shared__ float pU[2][128], pV[2][128];
    __shared__ float Us[128], Vs[128];
    __shared__ float pC[4][64];
    __shared__ float sAB[2];
    __shared__ float aggs[64], gi[192], gh[192];

    if (tid < 64) hs[tid] = hin[(size_t)bj*64 + tid];
    else if (tid < 112){
        int i = tid - 64;
        int node = base + i;
        float gv = g[(size_t)node*48 + j];
        wAs[i] = gv * hin[(size_t)node*64 + p0];
        wBs[i] = gv * hin[(size_t)node*64 + p0 + 1];
    }
    __syncthreads();
    if (tid < 2){
        const float* src = tid ? wBs : wAs;
        float s = 0.f;
        for (int i = 0; i < 48; i++) s += src[i];
        sAB[tid] = s;
    }
    {   // U/V partials
        int c = tid & 127, half = tid >> 7;
        const float* r2b = relu2 + ((size_t)base*48 + j)*128 + c;  // i-stride 6144
        float aU = 0.f, aV = 0.f;
        for (int ii = 0; ii < 24; ii++){
            int i = half*24 + ii;
            float v = r2b[(size_t)i*6144];
            aU += wAs[i]*v; aV += wBs[i]*v;
        }
        pU[half][c] = aU; pV[half][c] = aV;
    }
    __syncthreads();
    if (tid < 128){ Us[tid] = pU[0][tid] + pU[1][tid]; Vs[tid] = pV[0][tid] + pV[1][tid]; }
    __syncthreads();
    {   // agg = U@A_r + V@B_r
        int m = tid & 63, cg = tid >> 6;
        const float* Arp = A  + r*8192 + m;
        const float* Brp = Bm + r*8192 + m;
        float a = 0.f;
        for (int cc = 0; cc < 32; cc++){
            int c = cg*32 + cc;
            a += Us[c]*Arp[c*64] + Vs[c]*Brp[c*64];
        }
        pC[cg][m] = a;
    }
    __syncthreads();
    if (tid < 64){
        aggs[tid] = pC[0][tid] + pC[1][tid] + pC[2][tid] + pC[3][tid]
                  + sAB[0]*Ab[r*64 + tid] + sAB[1]*Bb[r*64 + tid];
    }
    __syncthreads();
    if (tid < 192){
        float gacc = bih[tid], hacc = bhh[tid];
        for (int k = 0; k < 64; k++){
            gacc += aggs[k] * wihT[k*192 + tid];
            hacc += hs[k]   * whhT[k*192 + tid];
        }
        gi[tid] = gacc; gh[tid] = hacc;
    }
    __syncthreads();
    if (tid < 64){
        float rr = sigmoidf_(gi[tid] + gh[tid]);
        float zz = sigmoidf_(gi[64+tid] + gh[64+tid]);
        float nn = tanhf(gi[128+tid] + rr*gh[128+tid]);
        float hnew = (1.f - zz)*nn + zz*hs[tid];
        hout[(size_t)bj*64 + tid] = mask[bj] * hnew;
    }
}

// ---------------------------------------------------------------------------
// K4: readout, 192 blocks (16 batches x 12 groups of 4 nodes), 256 threads.
// ---------------------------------------------------------------------------
__device__ __forceinline__ void rd_layer(
    const float* __restrict__ Xs, const float* __restrict__ W,
    const float* __restrict__ bias, float* __restrict__ Ys,
    int dim, int o, int ng, bool do_relu)
{
    float a0 = bias[o];
    float a1 = a0;
    for (int i = 0; i < dim; i += 4){
        float w0 = W[(size_t)(i+0)*128 + o];
        float w1 = W[(size_t)(i+1)*128 + o];
        float w2 = W[(size_t)(i+2)*128 + o];
        float w3 = W[(size_t)(i+3)*128 + o];
        const float4 x0 = *(const float4*)&Xs[ng*128 + i];
        const float4 x1 = *(const float4*)&Xs[(ng+2)*128 + i];
        a0 += x0.x*w0 + x0.y*w1 + x0.z*w2 + x0.w*w3;
        a1 += x1.x*w0 + x1.y*w1 + x1.z*w2 + x1.w*w3;
    }
    if (do_relu){ a0 = fmaxf(a0, 0.f); a1 = fmaxf(a1, 0.f); }
    Ys[ng*128 + o] = a0;
    Ys[(ng+2)*128 + o] = a1;
}

__global__ __launch_bounds__(256) void k_read(
    const float* __restrict__ hfirst, const float* __restrict__ hT,
    const float* __restrict__ mask,
    const float* __restrict__ w00, const float* __restrict__ b00,
    const float* __restrict__ w01, const float* __restrict__ b01,
    const float* __restrict__ w02, const float* __restrict__ b02,
    const float* __restrict__ w10, const float* __restrict__ b10,
    const float* __restrict__ w11, const float* __restrict__ b11,
    const float* __restrict__ w12, const float* __restrict__ b12,
    float* __restrict__ partial)
{
    __shared__ __align__(16) float xs[4*128];
    __shared__ __align__(16) float ys[4*128];
    __shared__ __align__(16) float zs[4*128];
    __shared__ __align__(16) float os0[4*128];
    __shared__ float mS[4];
    int tid = threadIdx.x;
    int b = blockIdx.x / 12, gg = blockIdx.x - b*12;
    int node0 = b*48 + gg*4;
    int o = tid & 127, ng = tid >> 7;
    if (tid < 4) mS[tid] = mask[node0 + tid];
    for (int i = tid; i < 4*128; i += 256){
        int r = i >> 7, c = i & 127;
        xs[i] = (c < 64) ? hfirst[(size_t)(node0+r)*64 + c]
                         : hT[(size_t)(node0+r)*64 + (c - 64)];
    }
    __syncthreads();
    rd_layer(xs,      w00, b00, ys,  128, o, ng, true);  __syncthreads();
    rd_layer(ys,      w01, b01, zs,  128, o, ng, true);  __syncthreads();
    rd_layer(zs,      w02, b02, os0, 128, o, ng, false); __syncthreads();
    rd_layer(xs + 64, w10, b10, ys,  64,  o, ng, true);  __syncthreads();
    rd_layer(ys,      w11, b11, zs,  128, o, ng, true);  __syncthreads();
    {
        float a0 = b12[o];
        float a1 = a0;
        for (int i = 0; i < 128; i += 4){
            float w0 = w12[(size_t)(i+0)*128 + o];
            float w1 = w12[(size_t)(i+1)*128 + o];
            float w2 = w12[(size_t)(i+2)*128 + o];
            float w3 = w12[(size_t)(i+3)*128 + o];
            const float4 x0 = *(const float4*)&zs[ng*128 + i];
            const float4 x1 = *(const float4*)&zs[(ng+2)*128 + i];
            a0 += x0.x*w0 + x0.y*w1 + x0.z*w2 + x0.w*w3;
            a1 += x1.x*w0 + x1.y*w1 + x1.z*w2 + x1.w*w3;
        }
        float s = mS[ng]   * os0[ng*128 + o]     * a0
                + mS[ng+2] * os0[(ng+2)*128 + o] * a1;
        __syncthreads();
        ys[ng*128 + o] = s;
    }
    __syncthreads();
    if (tid < 128)
        partial[(size_t)blockIdx.x*128 + tid] = ys[tid] + ys[128 + tid];
}

// ---------------------------------------------------------------------------
// K5: reduce 12 partials per batch + sigmoid
// ---------------------------------------------------------------------------
__global__ void k_final(const float* __restrict__ partial, float* __restrict__ out)
{
    int idx = blockIdx.x*256 + threadIdx.x;
    if (idx < B_*128){
        int b = idx >> 7, t = idx & 127;
        float s = 0.f;
        for (int c = 0; c < 12; c++) s += partial[(size_t)(b*12 + c)*128 + t];
        out[idx] = 1.0f / (1.0f + expf(-s));
    }
}

// ---------------------------------------------------------------------------
extern "C" void kernel_launch(void* const* d_in, const int* in_sizes, int n_in,
                              void* d_out, int out_size, void* d_ws, size_t ws_size,
                              hipStream_t stream)
{
    (void)in_sizes; (void)n_in; (void)out_size; (void)ws_size;
    const float* g    = (const float*)d_in[0];
    const float* h0   = (const float*)d_in[1];
    const float* e    = (const float*)d_in[2];
    const float* mw0  = (const float*)d_in[3];
    const float* mb0  = (const float*)d_in[4];
    const float* mw1  = (const float*)d_in[5];
    const float* mb1  = (const float*)d_in[6];
    const float* mw2  = (const float*)d_in[7];
    const float* mb2  = (const float*)d_in[8];
    const float* wih  = (const float*)d_in[9];
    const float* whh  = (const float*)d_in[10];
    const float* bih  = (const float*)d_in[11];
    const float* bhh  = (const float*)d_in[12];
    const float* r0w0 = (const float*)d_in[13];
    const float* r0b0 = (const float*)d_in[14];
    const float* r0w1 = (const float*)d_in[15];
    const float* r0b1 = (const float*)d_in[16];
    const float* r0w2 = (const float*)d_in[17];
    const float* r0b2 = (const float*)d_in[18];
    const float* r1w0 = (const float*)d_in[19];
    const float* r1b0 = (const float*)d_in[20];
    const float* r1w1 = (const float*)d_in[21];
    const float* r1b1 = (const float*)d_in[22];
    const float* r1w2 = (const float*)d_in[23];
    const float* r1b2 = (const float*)d_in[24];
    float* out = (float*)d_out;

    float* ws     = (float*)d_ws;
    float* A      = ws;                  // 3*128*64   = 24576
    float* Bm     = A      + 24576;      //              24576
    float* Ab     = Bm     + 24576;      // 3*64       = 192
    float* Bb     = Ab     + 192;        //              192
    float* hfirst = Bb     + 192;        // 768*64     = 49152
    float* hA     = hfirst + 49152;
    float* hB     = hA     + 49152;
    float* mask   = hB     + 49152;      //              768
    float* wihT   = mask   + 768;        // 64*192     = 12288
    float* whhT   = wihT   + 12288;      //              12288
    float* w1T    = whhT   + 12288;      // 128*128    = 16384
    float* part   = w1T    + 16384;      // 192*128    = 24576
    float* relu2  = part   + 24576;      // 36864*128  = 4718592
    // total ~ 5.0M floats = 19.1 MiB

    k_prep<<<449, 256, 0, stream>>>(mw2, mb2, h0, wih, whh, mw1,
                                    A, Bm, Ab, Bb, hfirst, mask, wihT, whhT, w1T);
    k_mlp<<<576, 256, 0, stream>>>(e, mw0, mb0, w1T, mb1, relu2);
    k_layer<<<768, 256, 0, stream>>>(hfirst, hA, relu2, A, Bm, Ab, Bb, g, mask,
                                     wihT, whhT, bih, bhh);
    k_layer<<<768, 256, 0, stream>>>(hA, hB, relu2, A, Bm, Ab, Bb, g, mask,
                                     wihT, whhT, bih, bhh);
    k_layer<<<768, 256, 0, stream>>>(hB, hA, relu2, A, Bm, Ab, Bb, g, mask,
                                     wihT, whhT, bih, bhh);
    k_read<<<192, 256, 0, stream>>>(hfirst, hA, mask,
                                    r0w0, r0b0, r0w1, r0b1, r0w2, r0b2,
                                    r1w0, r1b0, r1w1, r1b1, r1w2, r1b2, part);
    k_final<<<8, 256, 0, stream>>>(part, out);
}